// Round 6
// baseline (594.442 us; speedup 1.0000x reference)
//
#include <hip/hip_runtime.h>
#include <stdint.h>

#define DIM 16
#define HID 128
#define TN  64            // nodes per block
#define ROWF 132          // LDS row stride in floats (128 + 4 pad -> bank skew 4/row)
#define EPSF 1e-5f

// NaN-free tanh via v_exp + v_rcp (rel err ~1e-5; e+1=inf -> rcp=0 -> t=1)
__device__ __forceinline__ float safe_tanh(float x) {
    float a = fabsf(x);
    float e = __expf(2.0f * a);
    float r = __builtin_amdgcn_rcpf(e + 1.0f);
    return copysignf(1.0f - 2.0f * r, x);
}

// ---------------- Phase 1: edge scatter-add (proven, atomic-ceiling) ------
// 16 threads per edge. 102.4M dword atomics ~= 328 G/s memory-side ceiling.
__global__ void __launch_bounds__(256) edge_scatter_kernel(
    const float* __restrict__ nodes, const int* __restrict__ edges,
    const float* __restrict__ ew, float* __restrict__ agg_in,
    float* __restrict__ agg_out, int nEdges)
{
    int gid = blockIdx.x * 256 + threadIdx.x;
    int e = gid >> 4;
    if (e >= nEdges) return;
    int c = gid & 15;
    int src = edges[2 * e];
    int dst = edges[2 * e + 1];
    float w  = ew[e];
    float vs = nodes[src * DIM + c];
    float vd = nodes[dst * DIM + c];
    atomicAdd(&agg_in[dst * DIM + c], vs * w);
    atomicAdd(&agg_out[src * DIM + c], vd * w);
}

// ---------------- Phase 2: fused 4-layer MLP ------------------------------
// 256 threads, 64-node tile. Thread owns 4 rows x 8 cols:
//   c0 = (tid&15)*8  (16 col-groups cover 128 cols)
//   n0 = (tid>>4)*4  (16 row-groups cover 64 rows)
// k-step: 4 ds_read_b128 (X rows, broadcast across 16-lane col-groups,
// conflict-free) + 8 global b128 (weights, L1) + 128 FMA -> VALU-bound.
template<int K>
__device__ __forceinline__ void dense_ln_tanh(
    const float* __restrict__ W, const float* __restrict__ bias,
    const float* __restrict__ g, const float* __restrict__ be,
    float (&X)[TN][ROWF], int tid)
{
    const int c0 = (tid & 15) * 8;
    const int n0 = (tid >> 4) * 4;
    float acc[4][8];
    {
        float4 bA = *(const float4*)(bias + c0);
        float4 bB = *(const float4*)(bias + c0 + 4);
        #pragma unroll
        for (int i = 0; i < 4; ++i) {
            acc[i][0] = bA.x; acc[i][1] = bA.y; acc[i][2] = bA.z; acc[i][3] = bA.w;
            acc[i][4] = bB.x; acc[i][5] = bB.y; acc[i][6] = bB.z; acc[i][7] = bB.w;
        }
    }

    #pragma unroll 2
    for (int k = 0; k < K; k += 4) {
        float xr[4][4];
        #pragma unroll
        for (int i = 0; i < 4; ++i) {
            float4 t = *(const float4*)&X[n0 + i][k];
            xr[i][0] = t.x; xr[i][1] = t.y; xr[i][2] = t.z; xr[i][3] = t.w;
        }
        float wA[4][4], wB[4][4];
        #pragma unroll
        for (int kk = 0; kk < 4; ++kk) {
            float4 ta = *(const float4*)(W + (k + kk) * HID + c0);
            float4 tb = *(const float4*)(W + (k + kk) * HID + c0 + 4);
            wA[kk][0] = ta.x; wA[kk][1] = ta.y; wA[kk][2] = ta.z; wA[kk][3] = ta.w;
            wB[kk][0] = tb.x; wB[kk][1] = tb.y; wB[kk][2] = tb.z; wB[kk][3] = tb.w;
        }
        #pragma unroll
        for (int kk = 0; kk < 4; ++kk)
            #pragma unroll
            for (int i = 0; i < 4; ++i) {
                float xs = xr[i][kk];
                #pragma unroll
                for (int j = 0; j < 4; ++j) {
                    acc[i][j]     += xs * wA[kk][j];
                    acc[i][4 + j] += xs * wB[kk][j];
                }
            }
    }

    // LN stats from registers: in-thread over 8 cols, then 16 col-group lanes
    float s[4], q[4];
    #pragma unroll
    for (int i = 0; i < 4; ++i) {
        float ss = 0.f, qq = 0.f;
        #pragma unroll
        for (int j = 0; j < 8; ++j) { ss += acc[i][j]; qq += acc[i][j] * acc[i][j]; }
        s[i] = ss; q[i] = qq;
    }
    #pragma unroll
    for (int m = 1; m <= 8; m <<= 1) {
        #pragma unroll
        for (int i = 0; i < 4; ++i) {
            s[i] += __shfl_xor(s[i], m);
            q[i] += __shfl_xor(q[i], m);
        }
    }

    float4 gA  = *(const float4*)(g + c0);
    float4 gB  = *(const float4*)(g + c0 + 4);
    float4 eA  = *(const float4*)(be + c0);
    float4 eB  = *(const float4*)(be + c0 + 4);
    float gr[8]  = {gA.x, gA.y, gA.z, gA.w, gB.x, gB.y, gB.z, gB.w};
    float ber[8] = {eA.x, eA.y, eA.z, eA.w, eB.x, eB.y, eB.z, eB.w};

    __syncthreads();   // all X reads of this layer complete before overwrite
    #pragma unroll
    for (int i = 0; i < 4; ++i) {
        float mean = s[i] * (1.0f / HID);
        float var  = fmaxf(q[i] * (1.0f / HID) - mean * mean, 0.0f);
        float r = rsqrtf(var + EPSF);
        float o[8];
        #pragma unroll
        for (int j = 0; j < 8; ++j)
            o[j] = safe_tanh((acc[i][j] - mean) * r * gr[j] + ber[j]);
        *(float4*)&X[n0 + i][c0]     = make_float4(o[0], o[1], o[2], o[3]);
        *(float4*)&X[n0 + i][c0 + 4] = make_float4(o[4], o[5], o[6], o[7]);
    }
    __syncthreads();
}

__global__ void __launch_bounds__(256, 4) mlp_kernel(
    const float* __restrict__ agg_in, const float* __restrict__ agg_out,
    const float* __restrict__ nodes,
    const float* __restrict__ W1, const float* __restrict__ b1, const float* __restrict__ g1, const float* __restrict__ be1,
    const float* __restrict__ W2, const float* __restrict__ b2, const float* __restrict__ g2, const float* __restrict__ be2,
    const float* __restrict__ W3, const float* __restrict__ b3, const float* __restrict__ g3, const float* __restrict__ be3,
    const float* __restrict__ W4, const float* __restrict__ b4, const float* __restrict__ g4, const float* __restrict__ be4,
    float* __restrict__ out, int nNodes)
{
    __shared__ float X[TN][ROWF];

    const int tid = threadIdx.x;
    const int node0 = blockIdx.x * TN;

    // stage x = concat(agg_in, agg_out, nodes): 64 rows x 12 float4
    for (int i = tid; i < TN * 12; i += 256) {
        int n = i / 12, c4 = i - n * 12;
        int gn = node0 + n;
        float4 v = make_float4(0.f, 0.f, 0.f, 0.f);
        if (gn < nNodes) {
            if (c4 < 4)      v = *(const float4*)(agg_in  + gn * DIM + c4 * 4);
            else if (c4 < 8) v = *(const float4*)(agg_out + gn * DIM + (c4 - 4) * 4);
            else             v = *(const float4*)(nodes   + gn * DIM + (c4 - 8) * 4);
        }
        *(float4*)&X[n][c4 * 4] = v;
    }
    __syncthreads();

    dense_ln_tanh<48>(W1, b1, g1, be1, X, tid);
    dense_ln_tanh<128>(W2, b2, g2, be2, X, tid);
    dense_ln_tanh<128>(W3, b3, g3, be3, X, tid);

    // Layer 4: 128 -> 16, LN over 16, tanh. Thread owns 2 rows x 2 cols.
    {
        const int c0 = (tid & 7) * 2;   // col pair
        const int rg = tid >> 3;        // 0..31 -> rows rg*2, rg*2+1
        float a[2][2];
        a[0][0] = a[1][0] = b4[c0];
        a[0][1] = a[1][1] = b4[c0 + 1];
        #pragma unroll 2
        for (int k = 0; k < HID; k += 4) {
            float wv[4][2];
            #pragma unroll
            for (int kk = 0; kk < 4; ++kk) {
                float2 wt = *(const float2*)(W4 + (k + kk) * DIM + c0);
                wv[kk][0] = wt.x; wv[kk][1] = wt.y;
            }
            #pragma unroll
            for (int t = 0; t < 2; ++t) {
                float4 x = *(const float4*)&X[rg * 2 + t][k];
                float xs[4] = {x.x, x.y, x.z, x.w};
                #pragma unroll
                for (int kk = 0; kk < 4; ++kk) {
                    a[t][0] += xs[kk] * wv[kk][0];
                    a[t][1] += xs[kk] * wv[kk][1];
                }
            }
        }
        float s[2], q[2];
        #pragma unroll
        for (int t = 0; t < 2; ++t) {
            s[t] = a[t][0] + a[t][1];
            q[t] = a[t][0] * a[t][0] + a[t][1] * a[t][1];
        }
        #pragma unroll
        for (int m = 1; m <= 4; m <<= 1) {
            #pragma unroll
            for (int t = 0; t < 2; ++t) {
                s[t] += __shfl_xor(s[t], m);
                q[t] += __shfl_xor(q[t], m);
            }
        }
        float2 gt = *(const float2*)(g4 + c0);
        float2 et = *(const float2*)(be4 + c0);
        #pragma unroll
        for (int t = 0; t < 2; ++t) {
            int node = node0 + rg * 2 + t;
            if (node < nNodes) {
                float mean = s[t] * (1.0f / DIM);
                float var  = fmaxf(q[t] * (1.0f / DIM) - mean * mean, 0.0f);
                float r = rsqrtf(var + EPSF);
                float2 o;
                o.x = safe_tanh((a[t][0] - mean) * r * gt.x + et.x);
                o.y = safe_tanh((a[t][1] - mean) * r * gt.y + et.y);
                *(float2*)(out + (size_t)node * DIM + c0) = o;
            }
        }
    }
}

extern "C" void kernel_launch(void* const* d_in, const int* in_sizes, int n_in,
                              void* d_out, int out_size, void* d_ws, size_t ws_size,
                              hipStream_t stream)
{
    const float* nodes = (const float*)d_in[0];
    const int*   edges = (const int*)d_in[1];
    const float* ew    = (const float*)d_in[2];
    const float *W1 = (const float*)d_in[3],  *b1 = (const float*)d_in[4],
                *g1 = (const float*)d_in[5],  *be1 = (const float*)d_in[6];
    const float *W2 = (const float*)d_in[7],  *b2 = (const float*)d_in[8],
                *g2 = (const float*)d_in[9],  *be2 = (const float*)d_in[10];
    const float *W3 = (const float*)d_in[11], *b3 = (const float*)d_in[12],
                *g3 = (const float*)d_in[13], *be3 = (const float*)d_in[14];
    const float *W4 = (const float*)d_in[15], *b4 = (const float*)d_in[16],
                *g4 = (const float*)d_in[17], *be4 = (const float*)d_in[18];

    const int N = in_sizes[0] / DIM;     // 100000
    const int E = in_sizes[2];           // 3200000

    float* agg_in  = (float*)d_ws;
    float* agg_out = agg_in + (size_t)N * DIM;

    hipMemsetAsync(d_ws, 0, (size_t)2 * N * DIM * sizeof(float), stream);

    long long ethreads = (long long)E * 16;
    int egrid = (int)((ethreads + 255) / 256);
    edge_scatter_kernel<<<egrid, 256, 0, stream>>>(nodes, edges, ew,
                                                   agg_in, agg_out, E);

    int mgrid = (N + TN - 1) / TN;
    mlp_kernel<<<mgrid, 256, 0, stream>>>(agg_in, agg_out, nodes,
        W1, b1, g1, be1, W2, b2, g2, be2, W3, b3, g3, be3, W4, b4, g4, be4,
        (float*)d_out, N);
}